// Round 13
// baseline (60.778 us; speedup 1.0000x reference)
//
#include <hip/hip_runtime.h>

#define HOLE_P 0.05f
#define TW 64          // tile width
#define TH 64          // tile height
#define HALO 8
#define PRW 88         // padded row: 3 pad + guard + 80 content + guard + 3 pad
#define PRH 82         // guard + 80 content rows + guard
#define PLN 7216       // PRW*PRH
#define PWORDS 1804
#define QCAP 1536      // worklist capacity (expected ~440, ~27 sigma margin)

// Kernel 1: pack invalid = (hole_u < p) into bitmask, 8 px per byte, flat [c][y][x/8]
__global__ void k_mask(const float* __restrict__ hole_u, unsigned char* __restrict__ inv_mask) {
    int t = blockIdx.x * blockDim.x + threadIdx.x;    // 0 .. 2M-1
    const float* base = hole_u + (size_t)t * 8;
    float4 a = *reinterpret_cast<const float4*>(base);
    float4 b = *reinterpret_cast<const float4*>(base + 4);
    unsigned int m = (a.x < HOLE_P ? 1u : 0u)  | (a.y < HOLE_P ? 2u : 0u)  |
                     (a.z < HOLE_P ? 4u : 0u)  | (a.w < HOLE_P ? 8u : 0u)  |
                     (b.x < HOLE_P ? 16u : 0u) | (b.y < HOLE_P ? 32u : 0u) |
                     (b.z < HOLE_P ? 64u : 0u) | (b.w < HOLE_P ? 128u : 0u);
    inv_mask[t] = (unsigned char)m;
}

// Kernel 2: u_small[i][j] = OR over channels of invalid[c][2i][2j]
__global__ void k_us(const unsigned char* __restrict__ inv_mask, unsigned char* __restrict__ u_small) {
    int t = blockIdx.x * blockDim.x + threadIdx.x;    // 0 .. 65535
    int i  = t >> 7;
    int jb = t & 127;
    const unsigned char* p = inv_mask + (i << 8) + jb;
    unsigned int b = 0;
#pragma unroll
    for (int c = 0; c < 16; ++c) b |= p[c * 131072];
    unsigned int o = (b & 1u) | (((b >> 2) & 1u) << 8) | (((b >> 4) & 1u) << 16) | (((b >> 6) & 1u) << 24);
    *reinterpret_cast<unsigned int*>(u_small + i * 512 + jb * 4) = o;
}

// Kernel 3: d_small = cross-dilate(u_small), zero pad
__global__ void k_dil(const unsigned char* __restrict__ u_small, unsigned char* __restrict__ d_small) {
    int g = blockIdx.x * blockDim.x + threadIdx.x;
    int i = g >> 9, j = g & 511;
    unsigned char d = u_small[g];
    if (i > 0)   d |= u_small[g - 512];
    if (i < 511) d |= u_small[g + 512];
    if (j > 0)   d |= u_small[g - 1];
    if (j < 511) d |= u_small[g + 1];
    d_small[g] = d;
}

// Halo group index h (0..575) -> (row 0..79, col-group 0..19) of 80x80 content.
__device__ __forceinline__ void halo_map(int h, int& ly, int& lxg) {
    if (h < 160)      { ly = h / 20;                lxg = h - (h / 20) * 20; }
    else if (h < 320) { int t2 = h - 160; ly = 72 + t2 / 20; lxg = t2 - (t2 / 20) * 20; }
    else              { int t2 = h - 320; ly = 8 + (t2 >> 2); int q = t2 & 3; lxg = q < 2 ? q : q + 16; }
}

// State-word encode from src/invalid nibbles (bit i -> byte i).
__device__ __forceinline__ unsigned int enc_w(unsigned int src, unsigned int nib) {
    return ((src * 0x204081u) & 0x01010101u) | (((nib * 0x204081u) & 0x01010101u) << 7);
}

// Kernel 4: per-channel 64x64 tiles, halo 8, guard-ring padded LDS region.
// w byte: bit7 = invalid; low7: 0 = fillable, 1 = source, it+2 = filled at it,
// 0x7f = guard/out-of-image. Fillable pixels (~440/tile, known at init as
// ~src) go to a wave-compacted worklist; iterations process 1 px/lane.
// Early store: out = x for the WHOLE interior during encode (95% of output is
// final); epilogue scatters only interior-invalid pixels (worklist bit15) over
// still-L2-dirty lines. Exits: nothing filled, or no pending interior-invalid.
__global__ __launch_bounds__(512, 4) void k_fill(
    const float* __restrict__ x, const unsigned char* __restrict__ inv_mask,
    const unsigned char* __restrict__ d_small, float* __restrict__ out)
{
    __shared__ __align__(16) float v[PLN];
    __shared__ unsigned int w32[PWORDS];
    __shared__ unsigned short q[QCAP];
    __shared__ int qn;
    __shared__ int chgf[8], pendf[8];
    unsigned char* w = (unsigned char*)w32;

    const int tid = threadIdx.x;
    const int c   = blockIdx.z;
    const int by0 = blockIdx.y * TH;
    const int bx0 = blockIdx.x * TW;
    const float* xc = x + c * 1048576;
    const unsigned char* mc = inv_mask + c * 131072;
    float* oc = out + c * 1048576;
    const bool cornerTile = ((blockIdx.x == 0) | (blockIdx.x == 15)) &
                            ((blockIdx.y == 0) | (blockIdx.y == 15));

    if (tid < 8) { chgf[tid] = 0; pendf[tid] = 0; }
    if (tid == 0) qn = 0;
    if (tid < 204) {                      // guard ring + pads = 0x7f sentinel
        int wi;
        if (tid < 22)      wi = tid;                         // top row (row 0)
        else if (tid < 44) wi = 81 * 22 + (tid - 22);        // bottom row (row 81)
        else {                                               // rows 1..80, left/right word
            int r = ((tid - 44) >> 1) + 1;
            wi = r * 22 + (((tid - 44) & 1) ? 21 : 0);
        }
        w32[wi] = 0x7f7f7f7fu;
    }
    __syncthreads();                      // qn=0 visible before atomics

    // ---- global loads (max MLP: all issued up front) ----
    int r0  = tid >> 4, cg0 = tid & 15;
    int gy0 = by0 + r0,      gx0 = bx0 + cg0 * 4;
    int gy1 = by0 + r0 + 32;
    float4 xx0 = *reinterpret_cast<const float4*>(xc + gy0 * 1024 + gx0);
    float4 xx1 = *reinterpret_cast<const float4*>(xc + gy1 * 1024 + gx0);
    unsigned int mb0 = mc[(gy0 << 7) + (gx0 >> 3)];
    unsigned int mb1 = mc[(gy1 << 7) + (gx0 >> 3)];
    unsigned short dsA = *reinterpret_cast<const unsigned short*>(d_small + ((gy0 >> 1) << 9) + (gx0 >> 1));
    unsigned short dsB = *reinterpret_cast<const unsigned short*>(d_small + ((gy1 >> 1) << 9) + (gx0 >> 1));

    // halo: 576 groups = hA (all 512 threads) + hB (tid<64 -> h = tid+512)
    int aly, alxg, bly, blxg;
    halo_map(tid, aly, alxg);
    const bool hasB = (tid < 64);
    halo_map(hasB ? tid + 512 : 0, bly, blxg);
    int agy  = by0 - HALO + aly,  agx0 = bx0 - HALO + alxg * 4;
    int bgy  = by0 - HALO + bly,  bgx0 = bx0 - HALO + blxg * 4;
    bool ain = ((unsigned)agy < 1024u) & ((unsigned)agx0 < 1024u);
    bool bin = hasB & ((unsigned)bgy < 1024u) & ((unsigned)bgx0 < 1024u);
    float4 axx = make_float4(0.f, 0.f, 0.f, 0.f), bxx = axx;
    unsigned int amb = 0, bmb = 0; unsigned short ads = 0, bds = 0;
    if (ain) {
        int gi = agy * 1024 + agx0;
        axx = *reinterpret_cast<const float4*>(xc + gi);
        amb = mc[(agy << 7) + (agx0 >> 3)];
        ads = *reinterpret_cast<const unsigned short*>(d_small + ((agy >> 1) << 9) + (agx0 >> 1));
    }
    if (bin) {
        int gi = bgy * 1024 + bgx0;
        bxx = *reinterpret_cast<const float4*>(xc + gi);
        bmb = mc[(bgy << 7) + (bgx0 >> 3)];
        bds = *reinterpret_cast<const unsigned short*>(d_small + ((bgy >> 1) << 9) + (bgx0 >> 1));
    }

    // ---- encode + LDS writes + EARLY x-store; collect fillable nibbles ----
    unsigned int fN0, fN1, fNA = 0, fNB = 0;   // fillable nibbles
    unsigned int iN0, iN1, iNA = 0, iNB = 0;   // invalid nibbles
    int P0i0, P0i1, P0A, P0B;
    {
        unsigned int nib = (mb0 >> (gx0 & 7)) & 0xfu;
        unsigned int db = ((dsA & 0xffu) ? 0x3u : 0u) | ((dsA & 0xff00u) ? 0xcu : 0u);
        unsigned int src = db & ~nib & 0xfu;
        if (cornerTile && ((gy0 == 0) | (gy0 == 1023)))
            src |= (gx0 == 0 ? 1u : 0u) | (gx0 == 1020 ? 8u : 0u);
        unsigned int vs = src & ~nib;
        float4 vv;
        vv.x = (vs & 1u) ? xx0.x : 0.0f;
        vv.y = (vs & 2u) ? xx0.y : 0.0f;
        vv.z = (vs & 4u) ? xx0.z : 0.0f;
        vv.w = (vs & 8u) ? xx0.w : 0.0f;
        P0i0 = (9 + r0) * PRW + 12 + cg0 * 4;
        *reinterpret_cast<float4*>(&v[P0i0]) = vv;
        w32[P0i0 >> 2] = enc_w(src, nib);
        fN0 = ~src & 0xfu; iN0 = nib;
        *reinterpret_cast<float4*>(oc + gy0 * 1024 + gx0) = xx0;   // early store
    }
    {
        unsigned int nib = (mb1 >> (gx0 & 7)) & 0xfu;
        unsigned int db = ((dsB & 0xffu) ? 0x3u : 0u) | ((dsB & 0xff00u) ? 0xcu : 0u);
        unsigned int src = db & ~nib & 0xfu;
        if (cornerTile && ((gy1 == 0) | (gy1 == 1023)))
            src |= (gx0 == 0 ? 1u : 0u) | (gx0 == 1020 ? 8u : 0u);
        unsigned int vs = src & ~nib;
        float4 vv;
        vv.x = (vs & 1u) ? xx1.x : 0.0f;
        vv.y = (vs & 2u) ? xx1.y : 0.0f;
        vv.z = (vs & 4u) ? xx1.z : 0.0f;
        vv.w = (vs & 8u) ? xx1.w : 0.0f;
        P0i1 = (9 + r0 + 32) * PRW + 12 + cg0 * 4;
        *reinterpret_cast<float4*>(&v[P0i1]) = vv;
        w32[P0i1 >> 2] = enc_w(src, nib);
        fN1 = ~src & 0xfu; iN1 = nib;
        *reinterpret_cast<float4*>(oc + gy1 * 1024 + gx0) = xx1;   // early store
    }
    {   // halo A (all threads)
        P0A = (aly + 1) * PRW + 4 + alxg * 4;
        float4 vv = make_float4(0.f, 0.f, 0.f, 0.f);
        unsigned int ww = 0x7f7f7f7fu;
        if (ain) {
            unsigned int nib = (amb >> (agx0 & 7)) & 0xfu;
            unsigned int db = ((ads & 0xffu) ? 0x3u : 0u) | ((ads & 0xff00u) ? 0xcu : 0u);
            unsigned int src = db & ~nib & 0xfu;     // corners never in halo
            ww = enc_w(src, nib);
            vv.x = (src & 1u) ? axx.x : 0.0f;
            vv.y = (src & 2u) ? axx.y : 0.0f;
            vv.z = (src & 4u) ? axx.z : 0.0f;
            vv.w = (src & 8u) ? axx.w : 0.0f;
            fNA = ~src & 0xfu; iNA = nib;
        }
        *reinterpret_cast<float4*>(&v[P0A]) = vv;
        w32[P0A >> 2] = ww;
    }
    P0B = (bly + 1) * PRW + 4 + blxg * 4;
    if (hasB) {   // halo B (tid < 64)
        float4 vv = make_float4(0.f, 0.f, 0.f, 0.f);
        unsigned int ww = 0x7f7f7f7fu;
        if (bin) {
            unsigned int nib = (bmb >> (bgx0 & 7)) & 0xfu;
            unsigned int db = ((bds & 0xffu) ? 0x3u : 0u) | ((bds & 0xff00u) ? 0xcu : 0u);
            unsigned int src = db & ~nib & 0xfu;
            ww = enc_w(src, nib);
            vv.x = (src & 1u) ? bxx.x : 0.0f;
            vv.y = (src & 2u) ? bxx.y : 0.0f;
            vv.z = (src & 4u) ? bxx.z : 0.0f;
            vv.w = (src & 8u) ? bxx.w : 0.0f;
            fNB = ~src & 0xfu; iNB = nib;
        }
        *reinterpret_cast<float4*>(&v[P0B]) = vv;
        w32[P0B >> 2] = ww;
    }

    // ---- wave-compacted worklist build (prefix-sum + 1 atomic per wave) ----
    int cnt = __popc(fN0) + __popc(fN1) + __popc(fNA) + __popc(fNB);
    int lane = tid & 63;
    int xsum = cnt;
#pragma unroll
    for (int d = 1; d < 64; d <<= 1) {
        int y = __shfl_up(xsum, d, 64);
        if (lane >= d) xsum += y;
    }
    int base = 0;
    if (lane == 63) base = atomicAdd(&qn, xsum);
    base = __shfl(base, 63, 64);
    int idx = base + (xsum - cnt);
#define PUSH(m_, iv_, pd_, gp_) { unsigned int m = (m_); while (m) {            \
        int b = __builtin_ctz(m); m &= m - 1;                                   \
        unsigned int e = (unsigned int)((gp_) + b) | ((((iv_) >> b) & 1u) << 14)\
                         | ((((pd_) >> b) & 1u) << 15);                         \
        if (idx < QCAP) q[idx] = (unsigned short)e; ++idx; } }
    PUSH(fN0, iN0, fN0 & iN0, P0i0)        // interior: pend = fillable & invalid
    PUSH(fN1, iN1, fN1 & iN1, P0i1)
    PUSH(fNA, iNA, 0u, P0A)                // halo: never pend-relevant
    PUSH(fNB, iNB, 0u, P0B)
#undef PUSH
    __syncthreads();

    const int n = qn;
    if (n <= QCAP) {
        // ---- worklist Jacobi: 1 px/lane, packed; skip filled via state byte ----
        for (int it = 0; it < 8; ++it) {
            int chg = 0, pend = 0;
            unsigned int thr = (unsigned int)it;
            for (int i = tid; i < n; i += 512) {
                unsigned int e = q[i];
                int p = e & 0x1fffu;
                if (w[p] & 0x7fu) continue;            // already filled
                unsigned int qu = w[p - PRW] & 0x7fu;
                unsigned int qd = w[p + PRW] & 0x7fu;
                unsigned int ql = w[p - 1]   & 0x7fu;
                unsigned int qr = w[p + 1]   & 0x7fu;
                bool su = (qu - 1u) <= thr, sd = (qd - 1u) <= thr;
                bool sl = (ql - 1u) <= thr, sr = (qr - 1u) <= thr;
                float s = (su ? v[p - PRW] : 0.0f) + (sd ? v[p + PRW] : 0.0f)
                        + (sl ? v[p - 1]   : 0.0f) + (sr ? v[p + 1]   : 0.0f);
                int cn = (int)su + (int)sd + (int)sl + (int)sr;
                if (cn > 0) {
                    v[p] = s / (float)cn;              // reads gated by old states
                    w[p] = (unsigned char)((((e >> 14) & 1u) << 7) | (unsigned int)(it + 2));
                    chg = 1;
                } else {
                    pend |= (int)((e >> 15) & 1u);
                }
            }
            if (chg)  chgf[it] = 1;                    // benign all-write-1 races
            if (pend) pendf[it] = 1;
            __syncthreads();
            if (chgf[it] == 0 || pendf[it] == 0) break;
        }
        // ---- epilogue: scatter interior-invalid pixels over early-stored x ----
        for (int i = tid; i < n; i += 512) {
            unsigned int e = q[i];
            if (!(e & 0x8000u)) continue;              // interior & invalid only
            int p = e & 0x1fffu;
            int row = p / PRW;
            int col = p - row * PRW;
            oc[(by0 + row - 9) * 1024 + (bx0 + col - 12)] = v[p];
        }
    } else {
        // ---- overflow fallback (~never): dense sweeps over all words ----
        for (int it = 0; it < 8; ++it) {
            int chg = 0;
            unsigned int thr = (unsigned int)it;
            for (int wp = tid; wp < PWORDS; wp += 512) {
                unsigned int cw = w32[wp];
                unsigned int st = cw & 0x7f7f7f7fu;
                if ((((st - 0x01010101u) & ~st) & 0x80808080u) == 0u) continue;
                int p0 = wp * 4;
#pragma unroll
                for (int b = 0; b < 4; ++b) {
                    if (((st >> (8 * b)) & 0x7fu) != 0u) continue;  // exact per-byte
                    int p = p0 + b;
                    unsigned int qu = w[p - PRW] & 0x7fu, qd = w[p + PRW] & 0x7fu;
                    unsigned int ql = w[p - 1] & 0x7fu,   qr = w[p + 1] & 0x7fu;
                    bool su = (qu - 1u) <= thr, sd = (qd - 1u) <= thr;
                    bool sl = (ql - 1u) <= thr, sr = (qr - 1u) <= thr;
                    float s = (su ? v[p - PRW] : 0.0f) + (sd ? v[p + PRW] : 0.0f)
                            + (sl ? v[p - 1]   : 0.0f) + (sr ? v[p + 1]   : 0.0f);
                    int cn = (int)su + (int)sd + (int)sl + (int)sr;
                    if (cn > 0) {
                        v[p] = s / (float)cn;
                        w[p] = (unsigned char)(((cw >> (8 * b)) & 0x80u) | (unsigned int)(it + 2));
                        chg = 1;
                    }
                }
            }
            if (chg) chgf[it] = 1;
            __syncthreads();
            if (chgf[it] == 0) break;
        }
        // dense scatter of interior invalid bytes
        for (int wp = tid; wp < PWORDS; wp += 512) {
            unsigned int inv = w32[wp] & 0x80808080u;
            if (inv == 0u) continue;
            int p0 = wp * 4;
            int row = p0 / PRW;
            int col = p0 - row * PRW;
            if (row < 9 || row > 72 || col < 12 || col > 72) continue;  // interior words only
#pragma unroll
            for (int b = 0; b < 4; ++b)
                if (inv & (0x80u << (8 * b)))
                    oc[(by0 + row - 9) * 1024 + (bx0 + col + b - 12)] = v[p0 + b];
        }
    }

    // ---- corner patch: forced-source invalid corners aren't in the worklist ----
    if (cornerTile && tid == 0) {
        int ly = (blockIdx.y == 0) ? 9 : 72;
        int lx = (blockIdx.x == 0) ? 12 : 75;
        int p = ly * PRW + lx;
        if (w[p] & 0x80u) {
            int gy = (blockIdx.y == 0) ? 0 : 1023;
            int gx = (blockIdx.x == 0) ? 0 : 1023;
            oc[gy * 1024 + gx] = v[p];    // v=0 at forced-source invalid corner
        }
    }
}

extern "C" void kernel_launch(void* const* d_in, const int* in_sizes, int n_in,
                              void* d_out, int out_size, void* d_ws, size_t ws_size,
                              hipStream_t stream) {
    (void)in_sizes; (void)n_in; (void)out_size; (void)ws_size;
    const float* x      = (const float*)d_in[0];
    const float* hole_u = (const float*)d_in[1];
    float* out = (float*)d_out;
    unsigned char* u_small  = (unsigned char*)d_ws;           // 256 KiB
    unsigned char* d_small  = u_small + 262144;               // 256 KiB
    unsigned char* inv_mask = d_small + 262144;               // 2 MiB

    k_mask<<<8192, 256, 0, stream>>>(hole_u, inv_mask);       // 2M threads, 8 px each
    k_us  <<<256, 256, 0, stream>>>(inv_mask, u_small);
    k_dil <<<1024, 256, 0, stream>>>(u_small, d_small);
    dim3 grid(16, 16, 16);   // tiles_x, tiles_y, channels
    k_fill<<<grid, 512, 0, stream>>>(x, inv_mask, d_small, out);
}

// Round 14
// 54.300 us; speedup vs baseline: 1.1193x; 1.1193x over previous
//
#include <hip/hip_runtime.h>

#define HOLE_P 0.05f
#define TW 64          // tile width
#define TH 64          // tile height
#define HALO 8
#define PRW 88         // padded row: 3 pad + guard + 80 content + guard + 3 pad
#define PRH 82         // guard + 80 content rows + guard
#define PLN 7216       // PRW*PRH
#define PWORDS 1804
#define QCAP 1536      // worklist capacity (expected ~440, ~27 sigma margin)

// Kernel 1: pack invalid = (hole_u < p) into bitmask, 8 px per byte, flat [c][y][x/8]
__global__ void k_mask(const float* __restrict__ hole_u, unsigned char* __restrict__ inv_mask) {
    int t = blockIdx.x * blockDim.x + threadIdx.x;    // 0 .. 2M-1
    const float* base = hole_u + (size_t)t * 8;
    float4 a = *reinterpret_cast<const float4*>(base);
    float4 b = *reinterpret_cast<const float4*>(base + 4);
    unsigned int m = (a.x < HOLE_P ? 1u : 0u)  | (a.y < HOLE_P ? 2u : 0u)  |
                     (a.z < HOLE_P ? 4u : 0u)  | (a.w < HOLE_P ? 8u : 0u)  |
                     (b.x < HOLE_P ? 16u : 0u) | (b.y < HOLE_P ? 32u : 0u) |
                     (b.z < HOLE_P ? 64u : 0u) | (b.w < HOLE_P ? 128u : 0u);
    inv_mask[t] = (unsigned char)m;
}

// Kernel 2: u_small[i][j] = OR over channels of invalid[c][2i][2j]
__global__ void k_us(const unsigned char* __restrict__ inv_mask, unsigned char* __restrict__ u_small) {
    int t = blockIdx.x * blockDim.x + threadIdx.x;    // 0 .. 65535
    int i  = t >> 7;
    int jb = t & 127;
    const unsigned char* p = inv_mask + (i << 8) + jb;
    unsigned int b = 0;
#pragma unroll
    for (int c = 0; c < 16; ++c) b |= p[c * 131072];
    unsigned int o = (b & 1u) | (((b >> 2) & 1u) << 8) | (((b >> 4) & 1u) << 16) | (((b >> 6) & 1u) << 24);
    *reinterpret_cast<unsigned int*>(u_small + i * 512 + jb * 4) = o;
}

// Kernel 3: d_small = cross-dilate(u_small), zero pad
__global__ void k_dil(const unsigned char* __restrict__ u_small, unsigned char* __restrict__ d_small) {
    int g = blockIdx.x * blockDim.x + threadIdx.x;
    int i = g >> 9, j = g & 511;
    unsigned char d = u_small[g];
    if (i > 0)   d |= u_small[g - 512];
    if (i < 511) d |= u_small[g + 512];
    if (j > 0)   d |= u_small[g - 1];
    if (j < 511) d |= u_small[g + 1];
    d_small[g] = d;
}

// Halo group index h (0..575) -> (row 0..79, col-group 0..19) of 80x80 content.
__device__ __forceinline__ void halo_map(int h, int& ly, int& lxg) {
    if (h < 160)      { ly = h / 20;                lxg = h - (h / 20) * 20; }
    else if (h < 320) { int t2 = h - 160; ly = 72 + t2 / 20; lxg = t2 - (t2 / 20) * 20; }
    else              { int t2 = h - 320; ly = 8 + (t2 >> 2); int q = t2 & 3; lxg = q < 2 ? q : q + 16; }
}

// State-word encode from src/invalid nibbles (bit i -> byte i).
__device__ __forceinline__ unsigned int enc_w(unsigned int src, unsigned int nib) {
    return ((src * 0x204081u) & 0x01010101u) | (((nib * 0x204081u) & 0x01010101u) << 7);
}

// Reciprocal of cnt in {1,2,3,4} via selects (no div, no array->scratch).
__device__ __forceinline__ float rcp_cnt(int cn) {
    float lo = (cn == 1) ? 1.0f : 0.5f;          // cn in {1,2}
    float hi = (cn == 3) ? (1.0f / 3.0f) : 0.25f; // cn in {3,4}
    return (cn <= 2) ? lo : hi;
}

// Kernel 4: per-channel 64x64 tiles, halo 8, guard-ring padded LDS region.
// w byte: bit7 = invalid; low7: 0 = fillable, 1 = source, it+2 = filled at it,
// 0x7f = guard/out-of-image. v = x EVERYWHERE at init: v[p] is only read when
// p is a contributor (state 1 or filled), and fills overwrite v first — so
// non-source init values are never observed. Exception: the 4 forced-source
// invalid corners need v=0 (reference corner fixup) — patched under barrier.
// Fillable pixels (~440/tile, = ~src) go to a wave-compacted worklist;
// iterations process 1 px/lane. Exits: nothing filled, or no pending
// interior-invalid left (interior output then fixed). Epilogue: blended
// coalesced store out = bit7 ? v : x_reg (keeps WRITE at the 65.5 MB ideal).
__global__ __launch_bounds__(512, 4) void k_fill(
    const float* __restrict__ x, const unsigned char* __restrict__ inv_mask,
    const unsigned char* __restrict__ d_small, float* __restrict__ out)
{
    __shared__ __align__(16) float v[PLN];
    __shared__ unsigned int w32[PWORDS];
    __shared__ unsigned short q[QCAP];
    __shared__ int qn;
    __shared__ int chgf[8], pendf[8];
    unsigned char* w = (unsigned char*)w32;

    const int tid = threadIdx.x;
    const int c   = blockIdx.z;
    const int by0 = blockIdx.y * TH;
    const int bx0 = blockIdx.x * TW;
    const float* xc = x + c * 1048576;
    const unsigned char* mc = inv_mask + c * 131072;
    float* oc = out + c * 1048576;
    const bool cornerTile = ((blockIdx.x == 0) | (blockIdx.x == 15)) &
                            ((blockIdx.y == 0) | (blockIdx.y == 15));

    if (tid < 8) { chgf[tid] = 0; pendf[tid] = 0; }
    if (tid == 0) qn = 0;
    if (tid < 204) {                      // guard ring + pads = 0x7f sentinel
        int wi;
        if (tid < 22)      wi = tid;                         // top row (row 0)
        else if (tid < 44) wi = 81 * 22 + (tid - 22);        // bottom row (row 81)
        else {                                               // rows 1..80, left/right word
            int r = ((tid - 44) >> 1) + 1;
            wi = r * 22 + (((tid - 44) & 1) ? 21 : 0);
        }
        w32[wi] = 0x7f7f7f7fu;
    }
    __syncthreads();                      // qn=0 visible before atomics

    // ---- global loads (max MLP: all issued up front) ----
    int r0  = tid >> 4, cg0 = tid & 15;
    int gy0 = by0 + r0,      gx0 = bx0 + cg0 * 4;
    int gy1 = by0 + r0 + 32;
    float4 xx0 = *reinterpret_cast<const float4*>(xc + gy0 * 1024 + gx0);
    float4 xx1 = *reinterpret_cast<const float4*>(xc + gy1 * 1024 + gx0);
    unsigned int mb0 = mc[(gy0 << 7) + (gx0 >> 3)];
    unsigned int mb1 = mc[(gy1 << 7) + (gx0 >> 3)];
    unsigned short dsA = *reinterpret_cast<const unsigned short*>(d_small + ((gy0 >> 1) << 9) + (gx0 >> 1));
    unsigned short dsB = *reinterpret_cast<const unsigned short*>(d_small + ((gy1 >> 1) << 9) + (gx0 >> 1));

    // halo: 576 groups = hA (all 512 threads) + hB (tid<64 -> h = tid+512)
    int aly, alxg, bly, blxg;
    halo_map(tid, aly, alxg);
    const bool hasB = (tid < 64);
    halo_map(hasB ? tid + 512 : 0, bly, blxg);
    int agy  = by0 - HALO + aly,  agx0 = bx0 - HALO + alxg * 4;
    int bgy  = by0 - HALO + bly,  bgx0 = bx0 - HALO + blxg * 4;
    bool ain = ((unsigned)agy < 1024u) & ((unsigned)agx0 < 1024u);
    bool bin = hasB & ((unsigned)bgy < 1024u) & ((unsigned)bgx0 < 1024u);
    float4 axx = make_float4(0.f, 0.f, 0.f, 0.f), bxx = axx;
    unsigned int amb = 0, bmb = 0; unsigned short ads = 0, bds = 0;
    if (ain) {
        int gi = agy * 1024 + agx0;
        axx = *reinterpret_cast<const float4*>(xc + gi);
        amb = mc[(agy << 7) + (agx0 >> 3)];
        ads = *reinterpret_cast<const unsigned short*>(d_small + ((agy >> 1) << 9) + (agx0 >> 1));
    }
    if (bin) {
        int gi = bgy * 1024 + bgx0;
        bxx = *reinterpret_cast<const float4*>(xc + gi);
        bmb = mc[(bgy << 7) + (bgx0 >> 3)];
        bds = *reinterpret_cast<const unsigned short*>(d_small + ((bgy >> 1) << 9) + (bgx0 >> 1));
    }

    // ---- encode + LDS writes (v = x unconditionally); collect nibbles ----
    unsigned int fN0, fN1, fNA = 0, fNB = 0;   // fillable nibbles
    unsigned int iN0, iN1, iNA = 0, iNB = 0;   // invalid nibbles
    int P0i0, P0i1, P0A, P0B;
    {
        unsigned int nib = (mb0 >> (gx0 & 7)) & 0xfu;
        unsigned int db = ((dsA & 0xffu) ? 0x3u : 0u) | ((dsA & 0xff00u) ? 0xcu : 0u);
        unsigned int src = db & ~nib & 0xfu;
        if (cornerTile && ((gy0 == 0) | (gy0 == 1023)))
            src |= (gx0 == 0 ? 1u : 0u) | (gx0 == 1020 ? 8u : 0u);
        P0i0 = (9 + r0) * PRW + 12 + cg0 * 4;
        *reinterpret_cast<float4*>(&v[P0i0]) = xx0;
        w32[P0i0 >> 2] = enc_w(src, nib);
        fN0 = ~src & 0xfu; iN0 = nib;
    }
    {
        unsigned int nib = (mb1 >> (gx0 & 7)) & 0xfu;
        unsigned int db = ((dsB & 0xffu) ? 0x3u : 0u) | ((dsB & 0xff00u) ? 0xcu : 0u);
        unsigned int src = db & ~nib & 0xfu;
        if (cornerTile && ((gy1 == 0) | (gy1 == 1023)))
            src |= (gx0 == 0 ? 1u : 0u) | (gx0 == 1020 ? 8u : 0u);
        P0i1 = (9 + r0 + 32) * PRW + 12 + cg0 * 4;
        *reinterpret_cast<float4*>(&v[P0i1]) = xx1;
        w32[P0i1 >> 2] = enc_w(src, nib);
        fN1 = ~src & 0xfu; iN1 = nib;
    }
    {   // halo A (all threads)
        P0A = (aly + 1) * PRW + 4 + alxg * 4;
        unsigned int ww = 0x7f7f7f7fu;
        if (ain) {
            unsigned int nib = (amb >> (agx0 & 7)) & 0xfu;
            unsigned int db = ((ads & 0xffu) ? 0x3u : 0u) | ((ads & 0xff00u) ? 0xcu : 0u);
            unsigned int src = db & ~nib & 0xfu;     // corners never in halo
            ww = enc_w(src, nib);
            fNA = ~src & 0xfu; iNA = nib;
        }
        *reinterpret_cast<float4*>(&v[P0A]) = axx;   // 0 if out-of-image (never read)
        w32[P0A >> 2] = ww;
    }
    P0B = (bly + 1) * PRW + 4 + blxg * 4;
    if (hasB) {   // halo B (tid < 64)
        unsigned int ww = 0x7f7f7f7fu;
        if (bin) {
            unsigned int nib = (bmb >> (bgx0 & 7)) & 0xfu;
            unsigned int db = ((bds & 0xffu) ? 0x3u : 0u) | ((bds & 0xff00u) ? 0xcu : 0u);
            unsigned int src = db & ~nib & 0xfu;
            ww = enc_w(src, nib);
            fNB = ~src & 0xfu; iNB = nib;
        }
        *reinterpret_cast<float4*>(&v[P0B]) = bxx;
        w32[P0B >> 2] = ww;
    }

    // ---- wave-compacted worklist build (prefix-sum + 1 atomic per wave) ----
    int cnt = __popc(fN0) + __popc(fN1) + __popc(fNA) + __popc(fNB);
    int lane = tid & 63;
    int xsum = cnt;
#pragma unroll
    for (int d = 1; d < 64; d <<= 1) {
        int y = __shfl_up(xsum, d, 64);
        if (lane >= d) xsum += y;
    }
    int base = 0;
    if (lane == 63) base = atomicAdd(&qn, xsum);
    base = __shfl(base, 63, 64);
    int idx = base + (xsum - cnt);
#define PUSH(m_, iv_, pd_, gp_) { unsigned int m = (m_); while (m) {            \
        int b = __builtin_ctz(m); m &= m - 1;                                   \
        unsigned int e = (unsigned int)((gp_) + b) | ((((iv_) >> b) & 1u) << 14)\
                         | ((((pd_) >> b) & 1u) << 15);                         \
        if (idx < QCAP) q[idx] = (unsigned short)e; ++idx; } }
    PUSH(fN0, iN0, fN0 & iN0, P0i0)        // interior: pend = fillable & invalid
    PUSH(fN1, iN1, fN1 & iN1, P0i1)
    PUSH(fNA, iNA, 0u, P0A)                // halo: never pend-relevant
    PUSH(fNB, iNB, 0u, P0B)
#undef PUSH
    __syncthreads();

    // ---- corner patch: forced-source invalid corner must have v=0 (ref fixup).
    // Done post-barrier (owner's v=x store is ordered before), with its own
    // block-uniform barrier before any Jacobi read. Only 4 of 4096 tiles.
    if (cornerTile) {
        if (tid == 0) {
            int gy = (blockIdx.y == 0) ? 0 : 1023;
            int gx = (blockIdx.x == 0) ? 0 : 1023;
            int p = (9 + (gy - by0)) * PRW + 12 + (gx - bx0);
            if ((mc[(gy << 7) + (gx >> 3)] >> (gx & 7)) & 1u) v[p] = 0.0f;
        }
        __syncthreads();
    }

    const int n = qn;
    if (n <= QCAP) {
        // ---- worklist Jacobi: 1 px/lane, packed; skip filled via state byte ----
        for (int it = 0; it < 8; ++it) {
            int chg = 0, pend = 0;
            unsigned int thr = (unsigned int)it;
            for (int i = tid; i < n; i += 512) {
                unsigned int e = q[i];
                int p = e & 0x1fffu;
                if (w[p] & 0x7fu) continue;            // already filled
                unsigned int qu = w[p - PRW] & 0x7fu;
                unsigned int qd = w[p + PRW] & 0x7fu;
                unsigned int ql = w[p - 1]   & 0x7fu;
                unsigned int qr = w[p + 1]   & 0x7fu;
                bool su = (qu - 1u) <= thr, sd = (qd - 1u) <= thr;
                bool sl = (ql - 1u) <= thr, sr = (qr - 1u) <= thr;
                float s = (su ? v[p - PRW] : 0.0f) + (sd ? v[p + PRW] : 0.0f)
                        + (sl ? v[p - 1]   : 0.0f) + (sr ? v[p + 1]   : 0.0f);
                int cn = (int)su + (int)sd + (int)sl + (int)sr;
                if (cn > 0) {
                    v[p] = s * rcp_cnt(cn);            // reads gated by old states
                    w[p] = (unsigned char)((((e >> 14) & 1u) << 7) | (unsigned int)(it + 2));
                    chg = 1;
                } else {
                    pend |= (int)((e >> 15) & 1u);
                }
            }
            if (chg)  chgf[it] = 1;                    // benign all-write-1 races
            if (pend) pendf[it] = 1;
            __syncthreads();
            if (chgf[it] == 0 || pendf[it] == 0) break;
        }
    } else {
        // ---- overflow fallback (~never): dense sweeps over all words ----
        for (int it = 0; it < 8; ++it) {
            int chg = 0;
            unsigned int thr = (unsigned int)it;
            for (int wp = tid; wp < PWORDS; wp += 512) {
                unsigned int cw = w32[wp];
                unsigned int st = cw & 0x7f7f7f7fu;
                if ((((st - 0x01010101u) & ~st) & 0x80808080u) == 0u) continue;
                int p0 = wp * 4;
#pragma unroll
                for (int b = 0; b < 4; ++b) {
                    if (((st >> (8 * b)) & 0x7fu) != 0u) continue;  // exact per-byte
                    int p = p0 + b;
                    unsigned int qu = w[p - PRW] & 0x7fu, qd = w[p + PRW] & 0x7fu;
                    unsigned int ql = w[p - 1] & 0x7fu,   qr = w[p + 1] & 0x7fu;
                    bool su = (qu - 1u) <= thr, sd = (qd - 1u) <= thr;
                    bool sl = (ql - 1u) <= thr, sr = (qr - 1u) <= thr;
                    float s = (su ? v[p - PRW] : 0.0f) + (sd ? v[p + PRW] : 0.0f)
                            + (sl ? v[p - 1]   : 0.0f) + (sr ? v[p + 1]   : 0.0f);
                    int cn = (int)su + (int)sd + (int)sl + (int)sr;
                    if (cn > 0) {
                        v[p] = s * rcp_cnt(cn);
                        w[p] = (unsigned char)(((cw >> (8 * b)) & 0x80u) | (unsigned int)(it + 2));
                        chg = 1;
                    }
                }
            }
            if (chg) chgf[it] = 1;
            __syncthreads();
            if (chgf[it] == 0) break;
        }
    }
    // (both Jacobi exits pass through a __syncthreads: w/v stable here)

    // ---- epilogue: one blended coalesced store of the whole interior ----
#pragma unroll
    for (int k = 0; k < 2; ++k) {
        int r  = r0 + k * 32;
        int p0 = (9 + r) * PRW + 12 + cg0 * 4;
        unsigned int cw = w32[p0 >> 2];
        float4 vv = *reinterpret_cast<const float4*>(&v[p0]);
        float4 xx = (k == 0) ? xx0 : xx1;
        float4 o;
        o.x = (cw & 0x00000080u) ? vv.x : xx.x;
        o.y = (cw & 0x00008000u) ? vv.y : xx.y;
        o.z = (cw & 0x00800000u) ? vv.z : xx.z;
        o.w = (cw & 0x80000000u) ? vv.w : xx.w;
        *reinterpret_cast<float4*>(oc + (by0 + r) * 1024 + bx0 + cg0 * 4) = o;
    }
}

extern "C" void kernel_launch(void* const* d_in, const int* in_sizes, int n_in,
                              void* d_out, int out_size, void* d_ws, size_t ws_size,
                              hipStream_t stream) {
    (void)in_sizes; (void)n_in; (void)out_size; (void)ws_size;
    const float* x      = (const float*)d_in[0];
    const float* hole_u = (const float*)d_in[1];
    float* out = (float*)d_out;
    unsigned char* u_small  = (unsigned char*)d_ws;           // 256 KiB
    unsigned char* d_small  = u_small + 262144;               // 256 KiB
    unsigned char* inv_mask = d_small + 262144;               // 2 MiB

    k_mask<<<8192, 256, 0, stream>>>(hole_u, inv_mask);       // 2M threads, 8 px each
    k_us  <<<256, 256, 0, stream>>>(inv_mask, u_small);
    k_dil <<<1024, 256, 0, stream>>>(u_small, d_small);
    dim3 grid(16, 16, 16);   // tiles_x, tiles_y, channels
    k_fill<<<grid, 512, 0, stream>>>(x, inv_mask, d_small, out);
}